// Round 3
// baseline (685.336 us; speedup 1.0000x reference)
//
#include <hip/hip_runtime.h>

#define T_LEN 1460
#define CS 20              // timesteps per chunk; 73*20 = 1460
#define NCH 73
#define GB 4               // basins per block
#define NT (GB*CS)         // producer records per chunk = 80
#define IST 66             // padded chain-stride (dwords)

__device__ __forceinline__ float sigmf(float x) {
    float e = __builtin_amdgcn_exp2f(-1.44269504f * x);
    return __builtin_amdgcn_rcpf(1.0f + e);
}
__device__ __forceinline__ float rcpf(float x) { return __builtin_amdgcn_rcpf(x); }

__device__ __forceinline__ float lanef(float x, int l) {
    return __int_as_float(__builtin_amdgcn_readlane(__float_as_int(x), l));
}

// sum over each 16-lane row via full-rate DPP adds
__device__ __forceinline__ float row_sum16(float x) {
    x += __int_as_float(__builtin_amdgcn_update_dpp(0, __float_as_int(x), 0xB1, 0xF, 0xF, true));
    x += __int_as_float(__builtin_amdgcn_update_dpp(0, __float_as_int(x), 0x4E, 0xF, 0xF, true));
    x += __int_as_float(__builtin_amdgcn_update_dpp(0, __float_as_int(x), 0x141, 0xF, 0xF, true));
    x += __int_as_float(__builtin_amdgcn_update_dpp(0, __float_as_int(x), 0x140, 0xF, 0xF, true));
    return x;
}

__global__ __launch_bounds__(512, 2) void shm_pipe_kernel(
    const float* __restrict__ xc,    // [B, T, 3]
    const float* __restrict__ lo,    // [B, T, 8, 16]
    float* __restrict__ out)         // [B, T]
{
    // param rows: 0:sm 1:f_thr 2:sumax 3:inv_sumax 4:beta 5:perc 6:rkf 7:rki 8:rkb
    __shared__ float pbuf[2][CS][9][IST];   // 95040 B
    __shared__ float qbuf[2][CS][3][IST];   // 31680 B  {qf_in, qi_in, qb_in}
    __shared__ float bbuf[2][CS][4][4];     //  2560 B  {sn, lpq, et09, -} per basin

    const int lane  = threadIdx.x & 63;
    const int wid   = threadIdx.x >> 6;
    const int bbase = blockIdx.x * GB;
    const int g = lane >> 4, m = lane & 15;

    // ---------------- producer lane constants ----------------
    const int ip = lane >> 3;                 // param 0..7 (2 models per lane)
    const int mm = (2 * lane) & 15;
    const int prow = (ip <= 2) ? ip : ip + 1; // row in pbuf
    const float Ac = (ip==1)?10.f : (ip==2)?20.f : (ip==3)?1.f :
                     (ip==5)?1.f  : (ip==6)?1.f  : (ip==7)?10.f : 0.f;
    const float Bc = (ip==0)?10.f : (ip==1)?50.f : (ip==2)?680.f : (ip==3)?5.f :
                     (ip==4)?1.f  : (ip==5)?19.f : (ip==6)?99.f  : 990.f;
    const bool drcp = (ip >= 5);
    const bool dsm  = (ip == 0);
    const int pw = wid - 2;                   // producer index 0..5

    auto pload = [&](int cl, float2 (&raw)[14], float (&xv)[14]) {
        const int t0 = cl * CS;
#pragma unroll
        for (int r = 0; r < 14; ++r) {
            const int tau = pw + 6 * r;
            if (tau < NT) {
                const int gg = tau / CS, tl = tau - gg * CS;
                const size_t rowoff = (size_t)(bbase + gg) * T_LEN + (t0 + tl);
                raw[r] = *(const float2*)(lo + rowoff * 128 + 2 * lane);
                xv[r]  = (lane < 3) ? xc[rowoff * 3 + lane] : 0.f;
            }
        }
    };
    auto pwrite = [&](int cw, const float2 (&raw)[14], const float (&xv)[14]) {
        const int buf = cw & 1;
#pragma unroll
        for (int r = 0; r < 14; ++r) {
            const int tau = pw + 6 * r;
            if (tau < NT) {
                const int gg = tau / CS, tl = tau - gg * CS;
                const float prec = lanef(xv[r], 0);
                const float pet  = lanef(xv[r], 1);
                const float temp = lanef(xv[r], 2);
                const bool frozen = (temp < 0.f);
                const float tpos = frozen ? 0.f : temp;
                const float sn   = frozen ? prec : 0.f;
                const float lpq  = frozen ? 0.f : prec;
                const float et09 = 0.9f * pet;

                float v0 = fmaf(sigmf(raw[r].x), Bc, Ac);
                float v1 = fmaf(sigmf(raw[r].y), Bc, Ac);
                if (drcp) { v0 = rcpf(v0); v1 = rcpf(v1); }
                if (dsm)  { v0 *= tpos;    v1 *= tpos; }

                *(float2*)&pbuf[buf][tl][prow][gg * 16 + mm] = make_float2(v0, v1);
                if (ip == 2)
                    *(float2*)&pbuf[buf][tl][3][gg * 16 + mm] =
                        make_float2(rcpf(v0), rcpf(v1));
                if (lane == 0)
                    *(float4*)&bbuf[buf][tl][gg][0] = make_float4(sn, lpq, et09, 0.f);
            }
        }
    };

    // ---------------- stage 1 state (ss, su) ----------------
    float ss = 0.f, su = 5.f;
    // ---------------- stage 2 state (sf, si, sb) ----------------
    float sf = 1.f, si = 10.f, sb = 15.f;
    float rkf_r[CS], rki_r[CS], rkb_r[CS];
    float* op_g = out + (size_t)(bbase + g) * T_LEN;

    auto s2proc = [&](int cc) {
#pragma unroll
        for (int tl = 0; tl < CS; ++tl) {
            const float* qr = &qbuf[cc & 1][tl][0][lane];
            const float qf_in = qr[0], qi_in = qr[IST], qb_in = qr[2 * IST];
            sf += qf_in; const float qf_out = sf * rkf_r[tl]; sf -= qf_out;
            si += qi_in; const float qi_out = si * rki_r[tl]; si -= qi_out;
            sb += qb_in; const float qb_out = sb * rkb_r[tl]; sb -= qb_out;
            const float rs = row_sum16(qf_out + qi_out + qb_out) * 0.0625f;
            if (m == 0) op_g[cc * CS + tl] = rs;
        }
    };

    // producer register double-generation
    float2 rA[14], rB[14];
    float  xA[14], xB[14];

    // ---------------- prologue ----------------
    if (wid >= 2) {
        pload(0, rA, xA);
        pwrite(0, rA, xA);
        pload(1, rB, xB);
    }
    __syncthreads();

    // ---------------- main loop ----------------
    for (int c = 0; c < NCH; ++c) {
        if (wid == 0) {
            // stage 1: chunk c
            const int buf = c & 1;
#pragma unroll
            for (int tl = 0; tl < CS; ++tl) {
                const float* rec = &pbuf[buf][tl][0][lane];
                const float sm    = rec[0];
                const float f_thr = rec[IST];
                const float sumax = rec[2 * IST];
                const float inv   = rec[3 * IST];
                const float beta  = rec[4 * IST];
                const float perc  = rec[5 * IST];
                const float4 bx = *(const float4*)&bbuf[buf][tl][g][0];

                const float qs_out = fminf(ss, sm);
                ss = (ss - qs_out) + bx.x;
                const float qsp = qs_out + bx.y;
                const float qf_in = fmaxf(0.f, qsp - f_thr);
                const float qu_in = fminf(qsp, f_thr);

                const float u   = su * inv;
                const float psi = __builtin_amdgcn_exp2f(beta * __builtin_amdgcn_logf(u));
                const float su_temp = fmaf(qu_in, 1.f - psi, su);
                const float su2 = fminf(su_temp, sumax);
                const float ovf = fmaxf(0.f, su_temp - sumax);
                const float qu_out = fmaf(qu_in, psi, ovf);
                const float pwp = 0.8f * sumax;
                const float kth = (su2 <= pwp) ? su2 * inv : 1.f;
                su = fmaxf(0.f, su2 - bx.z * kth);

                const float qi_in = qu_out * perc;
                const float qb_in = qu_out - qi_in;
                float* qw = &qbuf[buf][tl][0][lane];
                qw[0]       = qf_in;
                qw[IST]     = qi_in;
                qw[2 * IST] = qb_in;
            }
        } else if (wid == 1) {
            // stage 2: chunk c-1, then preload rk for chunk c
            if (c > 0) s2proc(c - 1);
            const int buf = c & 1;
#pragma unroll
            for (int tl = 0; tl < CS; ++tl) {
                const float* rp = &pbuf[buf][tl][6][lane];
                rkf_r[tl] = rp[0];
                rki_r[tl] = rp[IST];
                rkb_r[tl] = rp[2 * IST];
            }
        } else {
            // producers: write chunk c+1, issue loads for chunk c+2
            if ((c & 1) == 0) {
                if (c < NCH - 1) pwrite(c + 1, rB, xB);
                if (c < NCH - 2) pload(c + 2, rA, xA);
            } else {
                if (c < NCH - 1) pwrite(c + 1, rA, xA);
                if (c < NCH - 2) pload(c + 2, rB, xB);
            }
        }
        __syncthreads();
    }

    // epilogue: stage 2 finishes the last chunk
    if (wid == 1) s2proc(NCH - 1);
}

extern "C" void kernel_launch(void* const* d_in, const int* in_sizes, int n_in,
                              void* d_out, int out_size, void* d_ws, size_t ws_size,
                              hipStream_t stream) {
    const float* xc = (const float*)d_in[0];   // [256,1460,3]
    const float* lo = (const float*)d_in[1];   // [256,1460,128]
    float* out = (float*)d_out;                // [256,1460,1]

    shm_pipe_kernel<<<dim3(64), dim3(512), 0, stream>>>(xc, lo, out);
}

// Round 4
// 299.659 us; speedup vs baseline: 2.2871x; 2.2871x over previous
//
#include <hip/hip_runtime.h>

#define T_LEN 1460
#define NBT (256 * T_LEN)          // 373,760 (b,t) records
#define NREC (NBT * 16)            // 5,980,160 chain records

__device__ __forceinline__ float sigmf(float x) {
    float e = __builtin_amdgcn_exp2f(-1.44269504f * x);
    return __builtin_amdgcn_rcpf(1.0f + e);
}
__device__ __forceinline__ float rcpf(float x) { return __builtin_amdgcn_rcpf(x); }

// sum over each 16-lane row via full-rate DPP adds
__device__ __forceinline__ float row_sum16(float x) {
    x += __int_as_float(__builtin_amdgcn_update_dpp(0, __float_as_int(x), 0xB1, 0xF, 0xF, true));
    x += __int_as_float(__builtin_amdgcn_update_dpp(0, __float_as_int(x), 0x4E, 0xF, 0xF, true));
    x += __int_as_float(__builtin_amdgcn_update_dpp(0, __float_as_int(x), 0x141, 0xF, 0xF, true));
    x += __int_as_float(__builtin_amdgcn_update_dpp(0, __float_as_int(x), 0x140, 0xF, 0xF, true));
    return x;
}

// ---------------------------------------------------------------------------
// Kernel A: pointwise parameter mapping (memory-bound, fully parallel).
// Record per (b,t,m): {sm, f_thr, sumax, beta, perc, 1/kf, 1/ki, 1/kb} (32B).
// Per (b,t): {sn, lpq, 0.9*pet, 0} (16B).
// ---------------------------------------------------------------------------
__global__ __launch_bounds__(256) void shm_param_kernel(
    const float* __restrict__ xc,   // [B,T,3]
    const float* __restrict__ lo,   // [B,T,8,16]
    float* __restrict__ R,          // [NBT*16][8]
    float* __restrict__ V)          // [NBT][4]
{
    const int tid = blockIdx.x * 256 + threadIdx.x;   // < NREC exactly
    const int m  = tid & 15;
    const int bt = tid >> 4;

    const float* lr = lo + (size_t)bt * 128 + m;
    const float r0 = lr[0],   r1 = lr[16],  r2 = lr[32],  r3 = lr[48];
    const float r4 = lr[64],  r5 = lr[80],  r6 = lr[96],  r7 = lr[112];

    const float* xp = xc + (size_t)bt * 3;
    const float prec = xp[0], pet = xp[1], temp = xp[2];
    const bool frozen = (temp < 0.f);
    const float tpos = frozen ? 0.f : temp;

    const float dd    = 10.f * sigmf(r0);
    const float sm    = tpos * dd;
    const float f_thr = fmaf(sigmf(r1), 50.f, 10.f);
    const float sumax = fmaf(sigmf(r2), 680.f, 20.f);
    const float beta  = fmaf(sigmf(r3), 5.f, 1.f);
    const float perc  = sigmf(r4);
    const float rkf   = rcpf(fmaf(sigmf(r5), 19.f, 1.f));
    const float rki   = rcpf(fmaf(sigmf(r6), 99.f, 1.f));
    const float rkb   = rcpf(fmaf(sigmf(r7), 990.f, 10.f));

    float4* Rp = (float4*)(R + (size_t)tid * 8);
    Rp[0] = make_float4(sm, f_thr, sumax, beta);
    Rp[1] = make_float4(perc, rkf, rki, rkb);
    if (m == 0)
        *(float4*)(V + (size_t)bt * 4) =
            make_float4(frozen ? prec : 0.f, frozen ? 0.f : prec, 0.9f * pet, 0.f);
}

// ---------------------------------------------------------------------------
// Kernel B: the irreducible serial scan. 64 blocks x 1 wave, no LDS, no
// barriers, 8-step register pipeline in NAMED float4 slots (no spill).
// ---------------------------------------------------------------------------
__global__ __launch_bounds__(64, 1) void shm_serial_kernel(
    const float* __restrict__ R,
    const float* __restrict__ V,
    float* __restrict__ out)        // [B,T]
{
    const int lane = threadIdx.x;
    const int m = lane & 15;
    const int chain = blockIdx.x * 64 + lane;
    const int b = chain >> 4;

    const float4* rp = (const float4*)(R + (size_t)b * T_LEN * 128 + m * 8);
    const float4* vp = (const float4*)(V + (size_t)b * T_LEN * 4);
    float* op = out + (size_t)b * T_LEN;

    float ss = 0.f, sf = 1.f, su = 5.f, si = 10.f, sb = 15.f;
    float4 qq;

#define LOADSLOT(A_, B_, V_, tt) \
    A_ = rp[(tt) * 32]; B_ = rp[(tt) * 32 + 1]; V_ = vp[tt];

#define STEP(A_, B_, V_, Q_) { \
    const float sm = A_.x, f_thr = A_.y, sumax = A_.z, beta = A_.w; \
    const float perc = B_.x, rkf = B_.y, rki = B_.z, rkb = B_.w; \
    const float qs_out = fminf(ss, sm); \
    ss = (ss - qs_out) + V_.x; \
    const float qsp = qs_out + V_.y; \
    const float qf_in = fmaxf(0.f, qsp - f_thr); \
    const float qu_in = fminf(qsp, f_thr); \
    sf += qf_in; const float qf_out = sf * rkf; sf -= qf_out; \
    const float inv = rcpf(sumax); \
    const float u = su * inv; \
    const float psi = __builtin_amdgcn_exp2f(beta * __builtin_amdgcn_logf(u)); \
    const float su_t = fmaf(qu_in, 1.f - psi, su); \
    const float su2 = fminf(su_t, sumax); \
    const float ovf = fmaxf(0.f, su_t - sumax); \
    const float qu_out = fmaf(qu_in, psi, ovf); \
    const float u2 = su2 * inv; \
    const float kth = (u2 <= 0.8f) ? u2 : 1.f; \
    su = fmaxf(0.f, su2 - V_.z * kth); \
    const float qi_in = qu_out * perc; \
    si += qi_in; const float qi_out = si * rki; si -= qi_out; \
    const float qb_in = qu_out - qi_in; \
    sb += qb_in; const float qb_out = sb * rkb; sb -= qb_out; \
    Q_ = row_sum16(qf_out + qi_out + qb_out) * 0.0625f; \
}

#define ST4(tt0) if (m == 0) *(float4*)(op + (tt0)) = qq;

    float4 c0a,c0b,c0v, c1a,c1b,c1v, c2a,c2b,c2v, c3a,c3b,c3v;
    float4 n0a,n0b,n0v, n1a,n1b,n1v, n2a,n2b,n2v, n3a,n3b,n3v;

    LOADSLOT(c0a,c0b,c0v, 0) LOADSLOT(c1a,c1b,c1v, 1)
    LOADSLOT(c2a,c2b,c2v, 2) LOADSLOT(c3a,c3b,c3v, 3)
    LOADSLOT(n0a,n0b,n0v, 4) LOADSLOT(n1a,n1b,n1v, 5)
    LOADSLOT(n2a,n2b,n2v, 6) LOADSLOT(n3a,n3b,n3v, 7)

    int tb = 0;
    for (; tb < T_LEN - 12; tb += 8) {   // tb = 0 .. 1440; consumes t < 1448
        STEP(c0a,c0b,c0v, qq.x) LOADSLOT(c0a,c0b,c0v, tb + 8)
        STEP(c1a,c1b,c1v, qq.y) LOADSLOT(c1a,c1b,c1v, tb + 9)
        STEP(c2a,c2b,c2v, qq.z) LOADSLOT(c2a,c2b,c2v, tb + 10)
        STEP(c3a,c3b,c3v, qq.w) LOADSLOT(c3a,c3b,c3v, tb + 11)
        ST4(tb)
        STEP(n0a,n0b,n0v, qq.x) LOADSLOT(n0a,n0b,n0v, tb + 12)
        STEP(n1a,n1b,n1v, qq.y) LOADSLOT(n1a,n1b,n1v, tb + 13)
        STEP(n2a,n2b,n2v, qq.z) LOADSLOT(n2a,n2b,n2v, tb + 14)
        STEP(n3a,n3b,n3v, qq.w) LOADSLOT(n3a,n3b,n3v, tb + 15)
        ST4(tb + 4)
    }
    // tb == 1448: c holds 1448..1451, n holds 1452..1455
    STEP(c0a,c0b,c0v, qq.x) LOADSLOT(c0a,c0b,c0v, 1456)
    STEP(c1a,c1b,c1v, qq.y) LOADSLOT(c1a,c1b,c1v, 1457)
    STEP(c2a,c2b,c2v, qq.z) LOADSLOT(c2a,c2b,c2v, 1458)
    STEP(c3a,c3b,c3v, qq.w) LOADSLOT(c3a,c3b,c3v, 1459)
    ST4(1448)
    STEP(n0a,n0b,n0v, qq.x) STEP(n1a,n1b,n1v, qq.y)
    STEP(n2a,n2b,n2v, qq.z) STEP(n3a,n3b,n3v, qq.w)
    ST4(1452)
    STEP(c0a,c0b,c0v, qq.x) STEP(c1a,c1b,c1v, qq.y)
    STEP(c2a,c2b,c2v, qq.z) STEP(c3a,c3b,c3v, qq.w)
    ST4(1456)
#undef LOADSLOT
#undef STEP
#undef ST4
}

// ---------------------------------------------------------------------------
// Fallback (proven round-2 kernel) if ws_size is too small.
// ---------------------------------------------------------------------------
#define CS 10
#define NCHUNK 146
#define IST 66

__device__ __forceinline__ float lane0f(float x) {
    return __int_as_float(__builtin_amdgcn_readlane(__float_as_int(x), 0));
}

__global__ __launch_bounds__(256, 1) void shm_pc_kernel(
    const float* __restrict__ xc, const float* __restrict__ lo,
    float* __restrict__ out)
{
    __shared__ float pbuf[2][CS][8][IST];
    __shared__ float bbuf[2][CS][4][4];

    const int lane  = threadIdx.x & 63;
    const int wid   = threadIdx.x >> 6;
    const int bbase = blockIdx.x * 4;

    const int ip = lane >> 3;
    const float A  = (ip==1)?10.f : (ip==2)?20.f : (ip==3)?1.f :
                     (ip==5)?1.f  : (ip==6)?1.f  : (ip==7)?10.f : 0.f;
    const float Bc = (ip==0)?10.f : (ip==1)?50.f : (ip==2)?680.f : (ip==3)?5.f :
                     (ip==4)?1.f  : (ip==5)?19.f : (ip==6)?99.f  : 990.f;
    const bool drcp = (ip >= 5);
    const bool dsm  = (ip == 0);
    const int  mm   = (2*lane) & 15;

    auto produce = [&](int cc, int buf) {
        const int t0 = cc * CS;
        float2 raw[14];
        float xr0[14], xr1[14], xr2[14];
#pragma unroll
        for (int r = 0; r < 14; ++r) {
            const int tau = (wid - 1) + 3 * r;
            if (tau < 40) {
                const int g  = tau / CS;
                const int tl = tau - g * CS;
                const size_t rowoff = (size_t)(bbase + g) * T_LEN + (t0 + tl);
                raw[r] = *(const float2*)(lo + rowoff * 128 + 2 * lane);
                if (lane == 0) {
                    const float* xp = xc + rowoff * 3;
                    xr0[r] = xp[0]; xr1[r] = xp[1]; xr2[r] = xp[2];
                }
            }
        }
#pragma unroll
        for (int r = 0; r < 14; ++r) {
            const int tau = (wid - 1) + 3 * r;
            if (tau < 40) {
                const int g  = tau / CS;
                const int tl = tau - g * CS;
                const float prec = lane0f(xr0[r]);
                const float pet  = lane0f(xr1[r]);
                const float temp = lane0f(xr2[r]);
                const bool frozen = (temp < 0.f);
                const float tpos = frozen ? 0.f : temp;
                const float sn   = frozen ? prec : 0.f;
                const float lpq  = frozen ? 0.f : prec;
                const float et09 = 0.9f * pet;

                float s0 = sigmf(raw[r].x);
                float s1 = sigmf(raw[r].y);
                float v0 = fmaf(s0, Bc, A);
                float v1 = fmaf(s1, Bc, A);
                v0 = drcp ? rcpf(v0) : v0;
                v1 = drcp ? rcpf(v1) : v1;
                v0 = dsm ? v0 * tpos : v0;
                v1 = dsm ? v1 * tpos : v1;

                float* dst = &pbuf[buf][tl][ip][g * 16 + mm];
                *(float2*)dst = make_float2(v0, v1);
                if (lane == 0)
                    *(float4*)&bbuf[buf][tl][g][0] = make_float4(sn, lpq, et09, 0.f);
            }
        }
    };

    const int g = lane >> 4, m = lane & 15;
    float ss = 0.f, sf = 1.f, su = 5.f, si = 10.f, sb = 15.f;
    float* op = out + (size_t)(bbase + g) * T_LEN;

    if (wid != 0) produce(0, 0);
    __syncthreads();

    for (int c = 0; c < NCHUNK; ++c) {
        if (wid == 0) {
            const int buf = c & 1;
#pragma unroll
            for (int tl = 0; tl < CS; ++tl) {
                const float* rec = &pbuf[buf][tl][0][lane];
                const float sm    = rec[0 * IST];
                const float f_thr = rec[1 * IST];
                const float sumax = rec[2 * IST];
                const float beta  = rec[3 * IST];
                const float perc  = rec[4 * IST];
                const float rkf   = rec[5 * IST];
                const float rki   = rec[6 * IST];
                const float rkb   = rec[7 * IST];
                const float4 bx = *(const float4*)&bbuf[buf][tl][g][0];

                float qs_out = fminf(ss, sm);
                ss = ss - qs_out + bx.x;
                float qsp = qs_out + bx.y;
                float qf_in = fmaxf(0.f, qsp - f_thr);
                float qu_in = fminf(qsp, f_thr);
                sf += qf_in;
                float qf_out = sf * rkf;
                sf -= qf_out;
                float inv_sumax = rcpf(sumax);
                float u = su * inv_sumax;
                float psi = __builtin_amdgcn_exp2f(beta * __builtin_amdgcn_logf(u));
                float su_temp = fmaf(qu_in, 1.f - psi, su);
                su = fminf(su_temp, sumax);
                float ovf = fmaxf(0.f, su_temp - sumax);
                float qu_out = fmaf(qu_in, psi, ovf);
                float pwp = 0.8f * sumax;
                float ktheta = (su <= pwp) ? su * inv_sumax : 1.f;
                float ret = bx.z * ktheta;
                su = fmaxf(0.f, su - ret);
                float qi_in = qu_out * perc;
                si += qi_in;
                float qi_out = si * rki;
                si -= qi_out;
                float qb_in = qu_out - qi_in;
                sb += qb_in;
                float qb_out = sb * rkb;
                sb -= qb_out;

                float q = row_sum16(qf_out + qi_out + qb_out) * 0.0625f;
                if (m == 0) op[c * CS + tl] = q;
            }
        } else if (c + 1 < NCHUNK) {
            produce(c + 1, (c + 1) & 1);
        }
        __syncthreads();
    }
}

extern "C" void kernel_launch(void* const* d_in, const int* in_sizes, int n_in,
                              void* d_out, int out_size, void* d_ws, size_t ws_size,
                              hipStream_t stream) {
    const float* xc = (const float*)d_in[0];   // [256,1460,3]
    const float* lo = (const float*)d_in[1];   // [256,1460,128]
    float* out = (float*)d_out;                // [256,1460,1]

    const size_t R_BYTES = (size_t)NREC * 32;  // 191,365,120
    const size_t V_BYTES = (size_t)NBT * 16;   //   5,980,160

    if (ws_size >= R_BYTES + V_BYTES) {
        float* R = (float*)d_ws;
        float* V = (float*)((char*)d_ws + R_BYTES);
        shm_param_kernel<<<dim3(NREC / 256), dim3(256), 0, stream>>>(xc, lo, R, V);
        shm_serial_kernel<<<dim3(64), dim3(64), 0, stream>>>(R, V, out);
    } else {
        shm_pc_kernel<<<dim3(64), dim3(256), 0, stream>>>(xc, lo, out);
    }
}